// Round 1
// baseline (4521.337 us; speedup 1.0000x reference)
//
#include <hip/hip_runtime.h>
#include <math.h>

#define NNEUR 300          // NN
#define NFEAT 20           // NF
#define MAUG  322          // 300 r + 20 image + 1 hold + 1 const(bias)
#define MAUGP 336          // padded to 4*84 for clean per-wave chunks
#define NOUT  50
#define NPMAC 100          // NPM
#define TSTEPS 500
#define BATCH 1024
#define XSTR  320          // padded n-stride for LDS state/partials

// Build augmented transposed weight matrix W[m][n] (MAUGP x NNEUR) in d_ws:
//   m in [0,300):   W[m][n] = J[n][m]          (recurrence, transposed)
//   m in [300,320): W[m][n] = I[n][m-300]      (input weights, transposed)
//   m == 320:       W[m][n] = S[n]             (hold scaling)
//   m == 321:       W[m][n] = Bb[n]            (bias, activation == 1)
//   m >= 322:       0                          (padding)
__global__ void build_w_kernel(const float* __restrict__ J,
                               const float* __restrict__ I,
                               const float* __restrict__ S,
                               const float* __restrict__ Bb,
                               float* __restrict__ W) {
    int e = blockIdx.x * 256 + threadIdx.x;
    if (e >= MAUGP * NNEUR) return;
    int m = e / NNEUR, n = e % NNEUR;
    float v = 0.0f;
    if (m < NNEUR)                 v = J[n * NNEUR + m];
    else if (m < NNEUR + NFEAT)    v = I[n * NFEAT + (m - NNEUR)];
    else if (m == NNEUR + NFEAT)   v = S[n];
    else if (m == NNEUR + NFEAT+1) v = Bb[n];
    W[e] = v;
}

// Persistent RNN kernel: 256 blocks x 256 threads; block owns batches [4*blk, 4*blk+4).
__global__ __launch_bounds__(256, 1) void rnn_kernel(
    const float* __restrict__ W,      // [MAUGP][NNEUR]
    const float* __restrict__ data,   // [T][21][B]
    const float* __restrict__ x0,     // [NNEUR]
    const float* __restrict__ fcw,    // [NOUT][NPMAC]
    const float* __restrict__ fcb,    // [NOUT]
    float* __restrict__ out)          // [T][B][NOUT]
{
    __shared__ __align__(16) float raug[MAUGP * 4];   // [m][b] augmented activations
    __shared__ __align__(16) float part[16 * XSTR];   // [wave][b][n] partial sums
    __shared__ __align__(16) float xs[4 * XSTR];      // [b][n] state x
    __shared__ float fcwt[NPMAC * NOUT];              // [p][o] transposed fc weights
    __shared__ float fcbs[NOUT];

    const int tid = threadIdx.x;
    const int blk = blockIdx.x;
    const int b0  = blk * 4;
    const int wid = tid >> 6;
    const int l   = tid & 63;

    // ---- init ----
    for (int i = tid; i < MAUGP * 4; i += 256) raug[i] = 0.0f;
    for (int i = tid; i < NPMAC * NOUT; i += 256) {
        int o = i / NPMAC, p = i % NPMAC;
        fcwt[p * NOUT + o] = fcw[i];
    }
    if (tid < NOUT) fcbs[tid] = fcb[tid];
    __syncthreads();  // raug zeroed before r-row fill (avoid WAW overlap confusion)
    for (int i = tid; i < NNEUR; i += 256) {
        float xv = x0[i];
        float rv = fmaxf(tanhf(xv), 0.0f);
        #pragma unroll
        for (int b = 0; b < 4; ++b) {
            xs[b * XSTR + i] = xv;
            raug[i * 4 + b] = rv;
        }
    }
    if (tid < 4) raug[(NNEUR + NFEAT + 1) * 4 + tid] = 1.0f;  // const row

    // prefetch data[t=0] slice (21 rows x 4 batch) into registers
    float4 dstage = make_float4(0.f, 0.f, 0.f, 0.f);
    if (tid < NFEAT + 1)
        dstage = *reinterpret_cast<const float4*>(data + (size_t)tid * BATCH + b0);
    __syncthreads();

    const int ms = 84 * wid;                       // this wave's m-chunk [ms, ms+84)

    for (int t = 0; t < TSTEPS; ++t) {
        // ---- Phase A: commit staged data[t] rows, prefetch data[t+1] ----
        if (tid < NFEAT + 1) {
            *reinterpret_cast<float4*>(&raug[(NNEUR + tid) * 4]) = dstage;
            if (t + 1 < TSTEPS)
                dstage = *reinterpret_cast<const float4*>(
                    data + ((size_t)(t + 1) * (NFEAT + 1) + tid) * BATCH + b0);
        }
        __syncthreads();

        // ---- Phase B: per-wave partial matvec over its m-chunk ----
        float acc[16];   // acc[i*4+b], n = 4*l + i
        float acct[4];   // tail n = 256 + l (l < 44)
        #pragma unroll
        for (int i = 0; i < 16; ++i) acc[i] = 0.0f;
        #pragma unroll
        for (int i = 0; i < 4; ++i) acct[i] = 0.0f;

        const float* Wp = W + (size_t)ms * NNEUR + 4 * l;
        const float* Wt = W + (size_t)ms * NNEUR + 256 + l;
        #pragma unroll 8
        for (int m = ms; m < ms + 84; ++m) {
            const float4 wv = *reinterpret_cast<const float4*>(Wp);
            float wt = 0.0f;
            if (l < 44) wt = *Wt;
            const float4 rv = *reinterpret_cast<const float4*>(&raug[m * 4]);
            float wvv[4] = {wv.x, wv.y, wv.z, wv.w};
            float rvv[4] = {rv.x, rv.y, rv.z, rv.w};
            #pragma unroll
            for (int i = 0; i < 4; ++i)
                #pragma unroll
                for (int b = 0; b < 4; ++b)
                    acc[i * 4 + b] += wvv[i] * rvv[b];
            #pragma unroll
            for (int b = 0; b < 4; ++b) acct[b] += wt * rvv[b];
            Wp += NNEUR; Wt += NNEUR;
        }
        // write partials: part[wid][b][n]
        #pragma unroll
        for (int b = 0; b < 4; ++b) {
            float4 v;
            v.x = acc[0 + b]; v.y = acc[4 + b]; v.z = acc[8 + b]; v.w = acc[12 + b];
            *reinterpret_cast<float4*>(&part[(wid * 4 + b) * XSTR + 4 * l]) = v;
        }
        if (l < 44) {
            #pragma unroll
            for (int b = 0; b < 4; ++b)
                part[(wid * 4 + b) * XSTR + 256 + l] = acct[b];
        }
        __syncthreads();

        // ---- Phase C: reduce partials, state update, write r into raug ----
        for (int p = tid; p < NNEUR * 4; p += 256) {
            int b = p & 3, n = p >> 2;
            float s = part[(0 * 4 + b) * XSTR + n]
                    + part[(1 * 4 + b) * XSTR + n]
                    + part[(2 * 4 + b) * XSTR + n]
                    + part[(3 * 4 + b) * XSTR + n];
            float xo  = xs[b * XSTR + n];
            float pre = xo + (s - xo) * 0.1f;     // x + tdx/10
            xs[b * XSTR + n] = pre;
            raug[n * 4 + b] = fmaxf(tanhf(pre), 0.0f);
        }
        __syncthreads();

        // ---- Phase D: y = r[:, :100] @ fcw.T + fcb ; store ----
        if (tid < 4 * NOUT) {
            int o = tid % NOUT, b = tid / NOUT;
            float y = fcbs[o];
            #pragma unroll 4
            for (int p = 0; p < NPMAC; ++p)
                y += raug[p * 4 + b] * fcwt[p * NOUT + o];
            out[((size_t)t * BATCH + b0 + b) * NOUT + o] = y;
        }
        // no barrier needed: next Phase A writes raug rows [300,321) which
        // Phase D does not touch; next barrier (after A) orders everything.
    }
}

extern "C" void kernel_launch(void* const* d_in, const int* in_sizes, int n_in,
                              void* d_out, int out_size, void* d_ws, size_t ws_size,
                              hipStream_t stream) {
    const float* data = (const float*)d_in[0];
    const float* J    = (const float*)d_in[1];
    const float* I    = (const float*)d_in[2];
    const float* S    = (const float*)d_in[3];
    const float* Bb   = (const float*)d_in[4];
    const float* x0   = (const float*)d_in[5];
    const float* fcw  = (const float*)d_in[6];
    const float* fcb  = (const float*)d_in[7];
    float* out = (float*)d_out;
    float* W   = (float*)d_ws;   // MAUGP*NNEUR*4 = 403,200 bytes

    int wtot = MAUGP * NNEUR;
    build_w_kernel<<<(wtot + 255) / 256, 256, 0, stream>>>(J, I, S, Bb, W);
    rnn_kernel<<<256, 256, 0, stream>>>(W, data, x0, fcw, fcb, out);
}

// Round 2
// 2767.396 us; speedup vs baseline: 1.6338x; 1.6338x over previous
//
#include <hip/hip_runtime.h>
#include <math.h>

#define NNEUR 300          // NN
#define NFEAT 20           // NF
#define NPAD  320          // padded n-dimension (5 per lane * 64 lanes)
#define MAUGP 336          // 300 r + 20 image + 1 hold + 1 const + 14 pad = 16*21
#define NOUT  50
#define NPMAC 100          // NPM
#define TSTEPS 500
#define BATCH 1024
#define NWAVE 16
#define MCHUNK 21          // m-rows per wave
#define RROWS 17           // rows held in registers
#define LROWS 4            // rows held in LDS
#define NJ 5               // n-values per lane: n = 64*j + l

// Augmented transposed weight matrix W[m][n], n padded to 320:
//   m in [0,300):   W[m][n] = J[n][m]
//   m in [300,320): W[m][n] = I[n][m-300]
//   m == 320:       W[m][n] = S[n]
//   m == 321:       W[m][n] = Bb[n]   (activation fixed at 1)
//   else / n>=300:  0
__global__ void build_w_kernel(const float* __restrict__ J,
                               const float* __restrict__ I,
                               const float* __restrict__ S,
                               const float* __restrict__ Bb,
                               float* __restrict__ W) {
    int e = blockIdx.x * 256 + threadIdx.x;
    if (e >= MAUGP * NPAD) return;
    int m = e / NPAD, n = e % NPAD;
    float v = 0.0f;
    if (n < NNEUR) {
        if (m < NNEUR)                   v = J[n * NNEUR + m];
        else if (m < NNEUR + NFEAT)      v = I[n * NFEAT + (m - NNEUR)];
        else if (m == NNEUR + NFEAT)     v = S[n];
        else if (m == NNEUR + NFEAT + 1) v = Bb[n];
    }
    W[e] = v;
}

// Persistent RNN: 256 blocks x 1024 threads (16 waves). Block owns 4 batch
// columns for all 500 steps. Weights fully on-chip: 85 VGPRs + 80KB LDS.
__global__ __launch_bounds__(1024, 4) void rnn_kernel(
    const float* __restrict__ W,      // [MAUGP][NPAD]
    const float* __restrict__ data,   // [T][21][B]
    const float* __restrict__ x0,     // [NNEUR]
    const float* __restrict__ fcw,    // [NOUT][NPMAC]
    const float* __restrict__ fcb,    // [NOUT]
    float* __restrict__ out)          // [T][B][NOUT]
{
    __shared__ __align__(16) float Wl[NWAVE][LROWS][NPAD];   // 80 KB weight rows
    __shared__ __align__(16) float part[8][4][NPAD];         // 40 KB partials
    __shared__ __align__(16) float raug[MAUGP][4];           // augmented activations
    __shared__ __align__(16) float xs[4][NPAD];              // state x
    __shared__ float fcwt[NPMAC][NOUT];                      // fc weights [p][o]
    __shared__ float fcbs[NOUT];

    const int tid = threadIdx.x;
    const int wid = tid >> 6;
    const int l   = tid & 63;
    const int b0  = blockIdx.x * 4;
    const int m0  = wid * MCHUNK;

    // ---- init: zero raug, load fc weights ----
    for (int i = tid; i < MAUGP * 4; i += 1024) ((float*)raug)[i] = 0.0f;
    for (int i = tid; i < NPMAC * NOUT; i += 1024) {
        int p = i / NOUT, o = i - p * NOUT;
        fcwt[p][o] = fcw[o * NPMAC + p];
    }
    if (tid < NOUT) fcbs[tid] = fcb[tid];
    __syncthreads();   // raug fully zeroed before row fills below

    for (int i = tid; i < NNEUR; i += 1024) {
        float xv = x0[i];
        float rv = fmaxf(tanhf(xv), 0.0f);
        #pragma unroll
        for (int b = 0; b < 4; ++b) { xs[b][i] = xv; raug[i][b] = rv; }
    }
    if (tid < 4) raug[NNEUR + NFEAT + 1][tid] = 1.0f;   // const row

    // ---- load this wave's weight chunk: 17 rows -> regs, 4 rows -> LDS ----
    float wr[RROWS * NJ];
    #pragma unroll
    for (int i = 0; i < RROWS; ++i)
        #pragma unroll
        for (int j = 0; j < NJ; ++j)
            wr[i * NJ + j] = W[(size_t)(m0 + i) * NPAD + 64 * j + l];
    #pragma unroll
    for (int i = 0; i < LROWS; ++i)
        #pragma unroll
        for (int j = 0; j < NJ; ++j)
            Wl[wid][i][64 * j + l] = W[(size_t)(m0 + RROWS + i) * NPAD + 64 * j + l];

    // prefetch data[t=0] slice (21 rows x 4 batch)
    float4 dstage = make_float4(0.f, 0.f, 0.f, 0.f);
    if (tid < NFEAT + 1)
        dstage = *reinterpret_cast<const float4*>(data + (size_t)tid * BATCH + b0);
    __syncthreads();

    for (int t = 0; t < TSTEPS; ++t) {
        // ---- Phase A: commit data[t], prefetch data[t+1] ----
        if (tid < NFEAT + 1) {
            *reinterpret_cast<float4*>(&raug[NNEUR + tid][0]) = dstage;
            if (t + 1 < TSTEPS)
                dstage = *reinterpret_cast<const float4*>(
                    data + ((size_t)(t + 1) * (NFEAT + 1) + tid) * BATCH + b0);
        }
        __syncthreads();

        // ---- Phase B: per-wave matvec over its 21-row m-chunk ----
        float acc[NJ * 4];
        #pragma unroll
        for (int k = 0; k < NJ * 4; ++k) acc[k] = 0.0f;

        #pragma unroll
        for (int i = 0; i < RROWS; ++i) {
            const float4 rv = *reinterpret_cast<const float4*>(&raug[m0 + i][0]);
            const float rb[4] = {rv.x, rv.y, rv.z, rv.w};
            #pragma unroll
            for (int j = 0; j < NJ; ++j)
                #pragma unroll
                for (int b = 0; b < 4; ++b)
                    acc[j * 4 + b] += wr[i * NJ + j] * rb[b];
        }
        #pragma unroll
        for (int i = 0; i < LROWS; ++i) {
            const float4 rv = *reinterpret_cast<const float4*>(&raug[m0 + RROWS + i][0]);
            const float rb[4] = {rv.x, rv.y, rv.z, rv.w};
            float wv[NJ];
            #pragma unroll
            for (int j = 0; j < NJ; ++j) wv[j] = Wl[wid][i][64 * j + l];
            #pragma unroll
            for (int j = 0; j < NJ; ++j)
                #pragma unroll
                for (int b = 0; b < 4; ++b)
                    acc[j * 4 + b] += wv[j] * rb[b];
        }

        // ---- two-stage partial reduce: waves 0-7 write, 8-15 RMW-add ----
        if (wid < 8) {
            #pragma unroll
            for (int j = 0; j < NJ; ++j)
                #pragma unroll
                for (int b = 0; b < 4; ++b)
                    part[wid][b][64 * j + l] = acc[j * 4 + b];
        }
        __syncthreads();
        if (wid >= 8) {
            #pragma unroll
            for (int j = 0; j < NJ; ++j)
                #pragma unroll
                for (int b = 0; b < 4; ++b)
                    part[wid - 8][b][64 * j + l] += acc[j * 4 + b];
        }
        __syncthreads();

        // ---- Phase C: reduce 8 partials, state update, write r ----
        {
            int b = tid / NPAD;
            int n = tid - b * NPAD;
            if (n < NNEUR) {
                float s = 0.0f;
                #pragma unroll
                for (int w8 = 0; w8 < 8; ++w8) s += part[w8][b][n];
                float xo  = xs[b][n];
                float pre = xo + (s - xo) * 0.1f;     // x + tdx/10
                xs[b][n] = pre;
                raug[n][b] = fmaxf(tanhf(pre), 0.0f);
            }
            if (tid < 256) {                           // tail: e=1024+tid -> b=3
                int n2 = 64 + tid;
                if (n2 < NNEUR) {
                    float s = 0.0f;
                    #pragma unroll
                    for (int w8 = 0; w8 < 8; ++w8) s += part[w8][3][n2];
                    float xo  = xs[3][n2];
                    float pre = xo + (s - xo) * 0.1f;
                    xs[3][n2] = pre;
                    raug[n2][3] = fmaxf(tanhf(pre), 0.0f);
                }
            }
        }
        __syncthreads();

        // ---- Phase D: y = r[:, :100] @ fcw.T + fcb ----
        if (tid < 4 * NOUT) {
            int b = tid / NOUT, o = tid - b * NOUT;
            float y = fcbs[o];
            #pragma unroll 4
            for (int p = 0; p < NPMAC; ++p)
                y += raug[p][b] * fcwt[p][o];
            out[((size_t)t * BATCH + b0 + b) * NOUT + o] = y;
        }
        // no barrier: Phase D reads raug[p<100]; next Phase A writes rows
        // >=300; the A-end barrier orders everything before the next C-write.
    }
}

extern "C" void kernel_launch(void* const* d_in, const int* in_sizes, int n_in,
                              void* d_out, int out_size, void* d_ws, size_t ws_size,
                              hipStream_t stream) {
    const float* data = (const float*)d_in[0];
    const float* J    = (const float*)d_in[1];
    const float* I    = (const float*)d_in[2];
    const float* S    = (const float*)d_in[3];
    const float* Bb   = (const float*)d_in[4];
    const float* x0   = (const float*)d_in[5];
    const float* fcw  = (const float*)d_in[6];
    const float* fcb  = (const float*)d_in[7];
    float* out = (float*)d_out;
    float* W   = (float*)d_ws;   // MAUGP*NPAD*4 = 430,080 bytes

    int wtot = MAUGP * NPAD;
    build_w_kernel<<<(wtot + 255) / 256, 256, 0, stream>>>(J, I, S, Bb, W);
    rnn_kernel<<<256, 1024, 0, stream>>>(W, data, x0, fcw, fcb, out);
}